// Round 5
// baseline (1648.358 us; speedup 1.0000x reference)
//
#include <hip/hip_runtime.h>
#include <cstddef>

#define Bx 2
#define Tn 4096
#define Hh 8

typedef unsigned short u16;
typedef unsigned int u32;
typedef __attribute__((ext_vector_type(8))) short short8;
typedef __attribute__((ext_vector_type(4))) float f32x4;

__device__ __forceinline__ float bf2f(u16 u) {
  u32 x = ((u32)u) << 16;
  return __uint_as_float(x);
}
__device__ __forceinline__ u16 f2bf(float f) {
  u32 x = __float_as_uint(f);
  u32 lsb = (x >> 16) & 1;
  x += 0x7fffu + lsb;
  return (u16)(x >> 16);
}
__device__ __forceinline__ u32 pack2(float a, float b) {
  return (u32)f2bf(a) | ((u32)f2bf(b) << 16);
}
__device__ __forceinline__ short8 cvt8(float4 f0, float4 f1) {
  uint4 p;
  p.x = pack2(f0.x, f0.y);
  p.y = pack2(f0.z, f0.w);
  p.z = pack2(f1.x, f1.y);
  p.w = pack2(f1.z, f1.w);
  return *(short8*)&p;
}
__device__ __forceinline__ void async16(u16* lds, const u16* g) {
  __builtin_amdgcn_global_load_lds((const __attribute__((address_space(1))) void*)g,
                                   (__attribute__((address_space(3))) void*)lds, 16, 0, 0);
}

// ---------------------------------------------------------------------------
// f32 -> bf16 elementwise convert
// ---------------------------------------------------------------------------
__global__ __launch_bounds__(256) void conv_bf16(const float* __restrict__ X,
                                                 u16* __restrict__ Xb) {
  int i = (blockIdx.x * 256 + threadIdx.x) * 8;
  float4 v0 = *(const float4*)&X[i];
  float4 v1 = *(const float4*)&X[i + 4];
  uint4 pv;
  pv.x = pack2(v0.x, v0.y);
  pv.y = pack2(v0.z, v0.w);
  pv.z = pack2(v1.x, v1.y);
  pv.w = pack2(v1.z, v1.w);
  *(uint4*)&Xb[i] = pv;
}

// ---------------------------------------------------------------------------
// Transpose-convert: W[K][N] f32 -> WT[N][K] bf16. 64x64 tiles.
// ---------------------------------------------------------------------------
__global__ __launch_bounds__(256) void transpose_bf16(const float* __restrict__ W,
                                                      u16* __restrict__ WT,
                                                      int K, int N) {
  __shared__ float tile[64][68];
  int nb = blockIdx.x, kb = blockIdx.y;
  int tid = threadIdx.x;
  int r = tid >> 4, c4 = (tid & 15) * 4;
#pragma unroll
  for (int p = 0; p < 4; p++) {
    int k = kb * 64 + p * 16 + r;
    float4 v = *(const float4*)&W[(size_t)k * N + nb * 64 + c4];
    tile[p * 16 + r][c4] = v.x;
    tile[p * 16 + r][c4 + 1] = v.y;
    tile[p * 16 + r][c4 + 2] = v.z;
    tile[p * 16 + r][c4 + 3] = v.w;
  }
  __syncthreads();
  int rn = tid >> 2, ck = (tid & 3) * 16;
#pragma unroll
  for (int s = 0; s < 2; s++) {
    int k0 = ck + s * 8;
    uint4 pv;
    pv.x = pack2(tile[k0 + 0][rn], tile[k0 + 1][rn]);
    pv.y = pack2(tile[k0 + 2][rn], tile[k0 + 3][rn]);
    pv.z = pack2(tile[k0 + 4][rn], tile[k0 + 5][rn]);
    pv.w = pack2(tile[k0 + 6][rn], tile[k0 + 7][rn]);
    *(uint4*)&WT[(size_t)(nb * 64 + rn) * K + kb * 64 + k0] = pv;
  }
}

// ---------------------------------------------------------------------------
// bf16 MFMA GEMM (m97 pattern). EPI=1: qkvz split epi. EPI=0: f32 store.
// ---------------------------------------------------------------------------
template<int EPI>
__global__ __launch_bounds__(256) void gemm_mfma(const u16* __restrict__ A,
                                                 const u16* __restrict__ Bt,
                                                 u16* __restrict__ O1,
                                                 u16* __restrict__ O2,
                                                 float* __restrict__ O3,
                                                 int Nfull) {
  const int K = 1024;
  __shared__ u16 As[128 * 32];
  __shared__ u16 Bs[128 * 32];
  int bn = blockIdx.x, bm = blockIdx.y;
  int tid = threadIdx.x;
  int wave = tid >> 6, lane = tid & 63;
  int wr = wave >> 1, wc = wave & 1;

  f32x4 acc[4][4];
#pragma unroll
  for (int i = 0; i < 4; i++)
#pragma unroll
    for (int j = 0; j < 4; j++) acc[i][j] = (f32x4){0.f, 0.f, 0.f, 0.f};

  const u16* Ab = A + (size_t)(bm * 128 + wave * 32 + (lane >> 2)) * K + (lane & 3) * 8;
  const u16* Bb = Bt + (size_t)(bn * 128 + wave * 32 + (lane >> 2)) * K + (lane & 3) * 8;
  u16* AsW = &As[(wave * 32) * 32];
  u16* BsW = &Bs[(wave * 32) * 32];

  int m_lane = lane & 15, k_lane = (lane >> 4) * 8;
  const u16* arow0 = &As[(wr * 64 + m_lane) * 32 + k_lane];
  const u16* brow0 = &Bs[(wc * 64 + m_lane) * 32 + k_lane];

  for (int kk = 0; kk < K; kk += 32) {
    __syncthreads();
    async16(AsW, Ab + kk);
    async16(AsW + 16 * 32, Ab + 16 * K + kk);
    async16(BsW, Bb + kk);
    async16(BsW + 16 * 32, Bb + 16 * K + kk);
    __syncthreads();
    short8 a[4], b[4];
#pragma unroll
    for (int t = 0; t < 4; t++) a[t] = *(const short8*)(arow0 + t * 16 * 32);
#pragma unroll
    for (int t = 0; t < 4; t++) b[t] = *(const short8*)(brow0 + t * 16 * 32);
#pragma unroll
    for (int i = 0; i < 4; i++)
#pragma unroll
      for (int j = 0; j < 4; j++)
        acc[i][j] = __builtin_amdgcn_mfma_f32_16x16x32_bf16(a[i], b[j], acc[i][j], 0, 0, 0);
  }

  int n0 = bn * 128;
  int cbase = wc * 64 + (lane & 15);
  int rbase = bm * 128 + wr * 64 + ((lane >> 4) * 4);
  if (EPI == 1) {
    int h = n0 >> 9, sub = (n0 >> 7) & 3;
    u16* dst;
    size_t stride;
    if (sub < 3) { dst = O1 + (size_t)(sub * 1024 + h * 128); stride = 3072; }
    else         { dst = O2 + (size_t)(h * 128);              stride = 1024; }
#pragma unroll
    for (int i = 0; i < 4; i++)
#pragma unroll
      for (int j = 0; j < 4; j++)
#pragma unroll
        for (int r = 0; r < 4; r++)
          dst[(size_t)(rbase + i * 16 + r) * stride + cbase + j * 16] = f2bf(acc[i][j][r]);
  } else {
#pragma unroll
    for (int i = 0; i < 4; i++)
#pragma unroll
      for (int j = 0; j < 4; j++)
#pragma unroll
        for (int r = 0; r < 4; r++)
          O3[(size_t)(rbase + i * 16 + r) * Nfull + n0 + cbase + j * 16] = acc[i][j][r];
  }
}

// ---------------------------------------------------------------------------
// ba = x @ W_ba then beta = sigmoid(b), g = -exp(A)*softplus(a+dt)
// ---------------------------------------------------------------------------
__global__ __launch_bounds__(128) void ba_kernel(const float* __restrict__ x,
                                                 const float* __restrict__ Wba,
                                                 const float* __restrict__ dtb,
                                                 const float* __restrict__ Alog,
                                                 float* __restrict__ betab,
                                                 float* __restrict__ gb) {
  __shared__ float xs[1024];
  __shared__ float part[8][16];
  int row = blockIdx.x, tid = threadIdx.x;
#pragma unroll
  for (int r = 0; r < 2; r++) {
    int f4 = r * 128 + tid;
    *(float4*)&xs[f4 * 4] = *(const float4*)&x[(size_t)row * 1024 + f4 * 4];
  }
  __syncthreads();
  int col = tid & 15, seg = tid >> 4;
  float a = 0.f;
  for (int k = seg * 128; k < seg * 128 + 128; k++) a += xs[k] * Wba[k * 16 + col];
  part[seg][col] = a;
  __syncthreads();
  if (tid < 8) {
    float bval = 0.f, aval = 0.f;
#pragma unroll
    for (int q = 0; q < 8; q++) { bval += part[q][tid * 2]; aval += part[q][tid * 2 + 1]; }
    betab[(size_t)row * 8 + tid] = 1.f / (1.f + expf(-bval));
    float spin = aval + dtb[tid];
    float sp = (spin > 20.f) ? spin : log1pf(expf(spin));
    gb[(size_t)row * 8 + tid] = -expf(Alog[tid]) * sp;
  }
}

// ---------------------------------------------------------------------------
// Per-chunk prep. One block per (chunk, bh). 256 threads.
// Outputs: qg [bh][t][128], kdT [bh][chunk][dk128][m64], vnT [bh][chunk][dv128][m64],
//          kcum [bh][t][128], attn [bh*64+n][64][64], egl.
// ---------------------------------------------------------------------------
__global__ __launch_bounds__(256) void prep(const u16* __restrict__ mixed,
                                            const float* __restrict__ cw,
                                            const float* __restrict__ gbuf,
                                            const float* __restrict__ betabuf,
                                            u16* __restrict__ qg,
                                            u16* __restrict__ kdT,
                                            u16* __restrict__ vnT,
                                            u16* __restrict__ kcum,
                                            u16* __restrict__ attn,
                                            float* __restrict__ egl) {
  __shared__ float sK[64 * 132];
  __shared__ float sQ[32 * 132];  // reused as tri[64*66]
  __shared__ float gc_s[64], bet_s[64], inv_s[64], red_s[256];

  int n = blockIdx.x, bh = blockIdx.y;
  int b = bh >> 3, h = bh & 7;
  int t0 = n * 64;
  int tid = threadIdx.x;
  const int rowg0 = b * Tn + t0;
  const int rowh0 = bh * Tn + t0;
  const size_t tbase = (size_t)(bh * 64 + n) * 8192;

  if (tid < 64) {
    red_s[tid] = gbuf[(size_t)(rowg0 + tid) * 8 + h];
    bet_s[tid] = betabuf[(size_t)(rowg0 + tid) * 8 + h];
  }
  __syncthreads();
  if (tid == 0) {
    float s = 0.f;
    for (int i = 0; i < 64; i++) { s += red_s[i]; gc_s[i] = s; }
  }
  __syncthreads();
  float gl = gc_s[63];

  // conv k -> sK, silu
  for (int r = 0; r < 32; r++) {
    int idx = r * 256 + tid;
    int i = idx >> 7, d = idx & 127;
    int col = 1024 + h * 128 + d;
    float a = 0.f;
    int tg = t0 + i - 3;
#pragma unroll
    for (int tap = 0; tap < 4; tap++)
      if (tg + tap >= 0) a += bf2f(mixed[(size_t)(b * Tn + tg + tap) * 3072 + col]) * cw[col * 4 + tap];
    a = a / (1.f + expf(-a));
    sK[i * 132 + d] = a;
  }
  __syncthreads();
  {
    int i = tid >> 2, p = tid & 3;
    float ss = 0.f;
    for (int d = p * 32; d < p * 32 + 32; d++) { float v = sK[i * 132 + d]; ss += v * v; }
    red_s[tid] = ss;
  }
  __syncthreads();
  if (tid < 64)
    inv_s[tid] = rsqrtf(red_s[tid * 4] + red_s[tid * 4 + 1] + red_s[tid * 4 + 2] + red_s[tid * 4 + 3] + 1e-6f);
  __syncthreads();
  for (int r = 0; r < 32; r++) {
    int idx = r * 256 + tid;
    int i = idx >> 7, d = idx & 127;
    sK[i * 132 + d] *= inv_s[i];
  }
  __syncthreads();
  // kdT[dk][m] = kn * exp(gl - gc_i)
  for (int r = 0; r < 32; r++) {
    int idx = r * 256 + tid;
    int d = idx >> 6, i = idx & 63;
    kdT[tbase + d * 64 + i] = f2bf(sK[i * 132 + d] * expf(gl - gc_s[i]));
  }

  // q halves
  for (int half = 0; half < 2; half++) {
    int i0 = half * 32;
    __syncthreads();
    for (int r = 0; r < 16; r++) {
      int idx = r * 256 + tid;
      int li = idx >> 7, d = idx & 127;
      int i = i0 + li;
      int col = h * 128 + d;
      float a = 0.f;
      int tg = t0 + i - 3;
#pragma unroll
      for (int tap = 0; tap < 4; tap++)
        if (tg + tap >= 0) a += bf2f(mixed[(size_t)(b * Tn + tg + tap) * 3072 + col]) * cw[col * 4 + tap];
      a = a / (1.f + expf(-a));
      sQ[li * 132 + d] = a;
    }
    __syncthreads();
    if (tid < 128) {
      int li = tid >> 2, p = tid & 3;
      float ss = 0.f;
      for (int d = p * 32; d < p * 32 + 32; d++) { float v = sQ[li * 132 + d]; ss += v * v; }
      red_s[tid] = ss;
    }
    __syncthreads();
    if (tid < 32)
      inv_s[tid] = rsqrtf(red_s[tid * 4] + red_s[tid * 4 + 1] + red_s[tid * 4 + 2] + red_s[tid * 4 + 3] + 1e-6f) *
                   0.08838834764831845f;
    __syncthreads();
    for (int r = 0; r < 16; r++) {
      int idx = r * 256 + tid;
      int li = idx >> 7, d = idx & 127;
      sQ[li * 132 + d] *= inv_s[li];
    }
    __syncthreads();
    for (int r = 0; r < 16; r++) {
      int idx = r * 256 + tid;
      int li = idx >> 7, d = idx & 127;
      int i = i0 + li;
      qg[(size_t)(rowh0 + i) * 128 + d] = f2bf(sQ[li * 132 + d] * expf(gc_s[i]));
    }
    // attn rows
    {
      int rp = tid >> 4, cg = tid & 15;
      float a_acc[2][4] = {};
      for (int d4 = 0; d4 < 128; d4 += 4) {
        float4 q0 = *(float4*)&sQ[(rp * 2 + 0) * 132 + d4];
        float4 q1 = *(float4*)&sQ[(rp * 2 + 1) * 132 + d4];
#pragma unroll
        for (int jj = 0; jj < 4; jj++) {
          float4 kv = *(float4*)&sK[(cg * 4 + jj) * 132 + d4];
          a_acc[0][jj] += q0.x * kv.x + q0.y * kv.y + q0.z * kv.z + q0.w * kv.w;
          a_acc[1][jj] += q1.x * kv.x + q1.y * kv.y + q1.z * kv.z + q1.w * kv.w;
        }
      }
#pragma unroll
      for (int rr = 0; rr < 2; rr++) {
        int i = i0 + rp * 2 + rr;
        float o[4];
#pragma unroll
        for (int jj = 0; jj < 4; jj++) {
          int j = cg * 4 + jj;
          o[jj] = (j <= i) ? a_acc[rr][jj] * expf(gc_s[i] - gc_s[j]) : 0.f;
        }
        uint2 ov;
        ov.x = pack2(o[0], o[1]);
        ov.y = pack2(o[2], o[3]);
        *(uint2*)&attn[(size_t)(bh * 64 + n) * 4096 + i * 64 + cg * 4] = ov;
      }
    }
  }

  // tri into sQ region (stride 66)
  float* tri = sQ;
  {
    int rp = tid >> 4, cg = tid & 15;
    float t_acc[4][4] = {};
    for (int d4 = 0; d4 < 128; d4 += 4) {
      float4 ka[4];
#pragma unroll
      for (int rr = 0; rr < 4; rr++) ka[rr] = *(float4*)&sK[(rp * 4 + rr) * 132 + d4];
#pragma unroll
      for (int jj = 0; jj < 4; jj++) {
        float4 kb = *(float4*)&sK[(cg * 4 + jj) * 132 + d4];
#pragma unroll
        for (int rr = 0; rr < 4; rr++)
          t_acc[rr][jj] += ka[rr].x * kb.x + ka[rr].y * kb.y + ka[rr].z * kb.z + ka[rr].w * kb.w;
      }
    }
    __syncthreads();
#pragma unroll
    for (int rr = 0; rr < 4; rr++)
#pragma unroll
      for (int jj = 0; jj < 4; jj++) {
        int i = rp * 4 + rr, j = cg * 4 + jj;
        tri[i * 66 + j] = (j < i) ? bet_s[i] * expf(gc_s[i] - gc_s[j]) * t_acc[rr][jj] : 0.f;
      }
  }
  __syncthreads();

  // forward substitution, both RHS
  {
    int mat = tid >> 7, c = tid & 127;
    float x[64];
    if (mat == 0) {
#pragma unroll
      for (int i = 0; i < 64; i++) x[i] = sK[i * 132 + c] * bet_s[i] * expf(gc_s[i]);
    } else {
      int col = 2048 + h * 128 + c;
      for (int i = 0; i < 64; i++) {
        float a = 0.f;
        int tg = t0 + i - 3;
#pragma unroll
        for (int tap = 0; tap < 4; tap++)
          if (tg + tap >= 0) a += bf2f(mixed[(size_t)(b * Tn + tg + tap) * 3072 + col]) * cw[col * 4 + tap];
        a = a / (1.f + expf(-a));
        x[i] = a * bet_s[i];
      }
    }
#pragma unroll
    for (int i = 1; i < 64; i++) {
      float s = x[i];
#pragma unroll
      for (int l = 0; l < i; l++) s -= tri[i * 66 + l] * x[l];
      x[i] = s;
    }
    if (mat == 0) {
#pragma unroll
      for (int i = 0; i < 64; i++) kcum[(size_t)(rowh0 + i) * 128 + c] = f2bf(x[i]);
    } else {
#pragma unroll
      for (int i = 0; i < 64; i += 2)
        *(u32*)&vnT[tbase + c * 64 + i] = pack2(x[i], x[i + 1]);
    }
  }
  if (tid == 0) egl[bh * 64 + n] = expf(gl);
}

// ---------------------------------------------------------------------------
// MFMA inter-chunk scan. Grid: 16 blocks (one per bh), 512 threads = 8 waves.
// Wave w owns dv-tile w: private ST (S^T 16x128 f32) and VN segments in LDS.
// NO block barriers in the loop — waves are fully independent; same-wave
// LDS write->read ordering is enforced by compiler lgkmcnt waits.
// 8 waves/CU give TLP to hide fragment-load latency; waves share kcum/qg/
// kdT/attn lines through L1.
// ---------------------------------------------------------------------------
__global__ __launch_bounds__(512) void scan_mfma(const u16* __restrict__ qg,
                                                 const u16* __restrict__ kdT,
                                                 const u16* __restrict__ vnT,
                                                 const u16* __restrict__ kcum,
                                                 const u16* __restrict__ attn,
                                                 const float* __restrict__ egl,
                                                 float* __restrict__ core) {
  __shared__ float STa[8][16 * 132];
  __shared__ float VNa[8][16 * 68];
  int bh = blockIdx.x;
  int wave = threadIdx.x >> 6;
  int lane = threadIdx.x & 63;
  float* ST = STa[wave];
  float* VN = VNa[wave];
  int dv0 = wave * 16;
  int b = bh >> 3, h = bh & 7;
  int q = lane >> 4, col = lane & 15;

  for (int r = lane; r < 16 * 132; r += 64) ST[r] = 0.f;

  for (int n = 0; n < 64; n++) {
    const u16* kc_b = kcum + (size_t)(bh * Tn + n * 64) * 128;
    const u16* qg_b = qg + (size_t)(bh * Tn + n * 64) * 128;
    const u16* at_b = attn + (size_t)(bh * 64 + n) * 4096;
    const u16* kt_b = kdT + (size_t)(bh * 64 + n) * 8192;
    const u16* vt_b = vnT + (size_t)(bh * 64 + n) * 8192 + (size_t)(dv0 + col) * 64;
    float eg = egl[bh * 64 + n];

    // S as B-fragments (bf16), plus negated copy
    short8 sb[4], sbn[4];
#pragma unroll
    for (int kt = 0; kt < 4; kt++) {
      float4 f0 = *(float4*)&ST[col * 132 + kt * 32 + q * 8];
      float4 f1 = *(float4*)&ST[col * 132 + kt * 32 + q * 8 + 4];
      sb[kt] = cvt8(f0, f1);
      uint4 u = *(uint4*)&sb[kt];
      u.x ^= 0x80008000u; u.y ^= 0x80008000u; u.z ^= 0x80008000u; u.w ^= 0x80008000u;
      sbn[kt] = *(short8*)&u;
    }

    // vn = vnew - kcum @ S
    f32x4 vn[4];
#pragma unroll
    for (int mt = 0; mt < 4; mt++) {
      uint2 vi = *(const uint2*)(vt_b + mt * 16 + q * 4);
      f32x4 a0;
      a0[0] = bf2f(vi.x & 0xffff); a0[1] = bf2f(vi.x >> 16);
      a0[2] = bf2f(vi.y & 0xffff); a0[3] = bf2f(vi.y >> 16);
#pragma unroll
      for (int kt = 0; kt < 4; kt++) {
        short8 af = *(const short8*)(kc_b + (size_t)(mt * 16 + col) * 128 + kt * 32 + q * 8);
        a0 = __builtin_amdgcn_mfma_f32_16x16x32_bf16(af, sbn[kt], a0, 0, 0, 0);
      }
      vn[mt] = a0;
    }
#pragma unroll
    for (int mt = 0; mt < 4; mt++)
      *(f32x4*)&VN[col * 68 + mt * 16 + q * 4] = vn[mt];
    // vn as B-fragments (same-wave LDS ordering via lgkmcnt)
    short8 vb[2];
#pragma unroll
    for (int kt2 = 0; kt2 < 2; kt2++) {
      float4 f0 = *(float4*)&VN[col * 68 + kt2 * 32 + q * 8];
      float4 f1 = *(float4*)&VN[col * 68 + kt2 * 32 + q * 8 + 4];
      vb[kt2] = cvt8(f0, f1);
    }

    // out = qg @ S + attn @ vn
#pragma unroll
    for (int mt = 0; mt < 4; mt++) {
      f32x4 o = (f32x4){0.f, 0.f, 0.f, 0.f};
#pragma unroll
      for (int kt = 0; kt < 4; kt++) {
        short8 af = *(const short8*)(qg_b + (size_t)(mt * 16 + col) * 128 + kt * 32 + q * 8);
        o = __builtin_amdgcn_mfma_f32_16x16x32_bf16(af, sb[kt], o, 0, 0, 0);
      }
#pragma unroll
      for (int kt2 = 0; kt2 < 2; kt2++) {
        short8 af = *(const short8*)(at_b + (mt * 16 + col) * 64 + kt2 * 32 + q * 8);
        o = __builtin_amdgcn_mfma_f32_16x16x32_bf16(af, vb[kt2], o, 0, 0, 0);
      }
      size_t rowb = (size_t)(b * Tn) + n * 64 + mt * 16 + q * 4;
#pragma unroll
      for (int r2 = 0; r2 < 4; r2++)
        core[(rowb + r2) * 1024 + h * 128 + dv0 + col] = o[r2];
    }

    // S = eg*S + kdT @ vn
#pragma unroll
    for (int t = 0; t < 8; t++) {
      f32x4 s0 = *(f32x4*)&ST[col * 132 + t * 16 + q * 4];
      s0[0] *= eg; s0[1] *= eg; s0[2] *= eg; s0[3] *= eg;
#pragma unroll
      for (int kt2 = 0; kt2 < 2; kt2++) {
        short8 af = *(const short8*)(kt_b + (size_t)(t * 16 + col) * 64 + kt2 * 32 + q * 8);
        s0 = __builtin_amdgcn_mfma_f32_16x16x32_bf16(af, vb[kt2], s0, 0, 0, 0);
      }
      *(f32x4*)&ST[col * 132 + t * 16 + q * 4] = s0;
    }
  }
}

// ---------------------------------------------------------------------------
// Gated RMSNorm; writes bf16 coreb (A-operand of out GEMM).
// ---------------------------------------------------------------------------
__global__ __launch_bounds__(256) void gnorm(const float* __restrict__ core,
                                             const u16* __restrict__ z,
                                             const float* __restrict__ nw,
                                             u16* __restrict__ coreb) {
  __shared__ float red[256];
  __shared__ float rstd[8];
  int row = blockIdx.x, tid = threadIdx.x;
  float4 c4 = *(const float4*)&core[(size_t)row * 1024 + tid * 4];
  uint2 zl = *(const uint2*)&z[(size_t)row * 1024 + tid * 4];
  float4 z4;
  z4.x = bf2f(zl.x & 0xffff); z4.y = bf2f(zl.x >> 16);
  z4.z = bf2f(zl.y & 0xffff); z4.w = bf2f(zl.y >> 16);
  red[tid] = c4.x * c4.x + c4.y * c4.y + c4.z * c4.z + c4.w * c4.w;
  __syncthreads();
  if (tid < 8) {
    float s = 0.f;
    for (int t2 = tid * 32; t2 < tid * 32 + 32; t2++) s += red[t2];
    rstd[tid] = rsqrtf(s * (1.f / 128.f) + 1e-6f);
  }
  __syncthreads();
  float rs = rstd[tid >> 5];
  int d0 = (tid * 4) & 127;
  float4 w4 = *(const float4*)&nw[d0];
  float4 o;
  o.x = c4.x * rs * w4.x * (z4.x / (1.f + expf(-z4.x)));
  o.y = c4.y * rs * w4.y * (z4.y / (1.f + expf(-z4.y)));
  o.z = c4.z * rs * w4.z * (z4.z / (1.f + expf(-z4.z)));
  o.w = c4.w * rs * w4.w * (z4.w / (1.f + expf(-z4.w)));
  uint2 pv;
  pv.x = pack2(o.x, o.y);
  pv.y = pack2(o.z, o.w);
  *(uint2*)&coreb[(size_t)row * 1024 + tid * 4] = pv;
}

// ---------------------------------------------------------------------------
extern "C" void kernel_launch(void* const* d_in, const int* in_sizes, int n_in,
                              void* d_out, int out_size, void* d_ws, size_t ws_size,
                              hipStream_t stream) {
  const float* x     = (const float*)d_in[0];
  const float* Wqkvz = (const float*)d_in[1];
  const float* Wba   = (const float*)d_in[2];
  const float* convw = (const float*)d_in[3];
  const float* dtb   = (const float*)d_in[4];
  const float* Alog  = (const float*)d_in[5];
  const float* nw    = (const float*)d_in[6];
  const float* Wout  = (const float*)d_in[7];
  float* out = (float*)d_out;

  // Workspace layout, total 143,134,720 B. Aliases lifetime-disjoint.
  char* w = (char*)d_ws;
  u16*   mixed = (u16*)w;                      // 50,331,648 B
  float* core  = (float*)w;                    // 33,554,432 B (aliases mixed)
  u16*   coreb = (u16*)(w + 33554432);         // 16,777,216 B
  u16*   zb    = (u16*)(w + 50331648);         // 16,777,216 B
  float* betab = (float*)(w + 67108864);       //    262,144 B
  float* gb    = (float*)(w + 67371008);       //    262,144 B
  u16*   qgB   = (u16*)(w + 67633152);         // 16,777,216 B
  u16*   xb    = (u16*)(w + 67633152);         // (alias, dead before prep)
  u16*   kdTB  = (u16*)(w + 84410368);         // 16,777,216 B
  u16*   WqT   = (u16*)(w + 84410368);         // (alias, dead before prep)
  u16*   vnTB  = (u16*)(w + 101187584);        // 16,777,216 B
  u16*   kcB   = (u16*)(w + 117964800);        // 16,777,216 B
  u16*   WoT   = (u16*)(w + 117964800);        // (alias, written after scan)
  u16*   atB   = (u16*)(w + 134742016);        //  8,388,608 B
  float* eglB  = (float*)(w + 143130624);      //      4,096 B

  conv_bf16<<<dim3(4096), 256, 0, stream>>>(x, xb);
  transpose_bf16<<<dim3(64, 16), 256, 0, stream>>>(Wqkvz, WqT, 1024, 4096);
  gemm_mfma<1><<<dim3(32, 64), 256, 0, stream>>>(xb, WqT, mixed, zb, nullptr, 4096);
  ba_kernel<<<dim3(8192), 128, 0, stream>>>(x, Wba, dtb, Alog, betab, gb);
  prep<<<dim3(64, 16), 256, 0, stream>>>(mixed, convw, gb, betab, qgB, kdTB, vnTB, kcB, atB, eglB);
  scan_mfma<<<dim3(16), 512, 0, stream>>>(qgB, kdTB, vnTB, kcB, atB, eglB, core);
  transpose_bf16<<<dim3(16, 16), 256, 0, stream>>>(Wout, WoT, 1024, 1024);
  gnorm<<<dim3(8192), 256, 0, stream>>>(core, zb, nw, coreb);
  gemm_mfma<0><<<dim3(8, 64), 256, 0, stream>>>(coreb, WoT, nullptr, nullptr, out, 1024);
}

// Round 6
// 951.010 us; speedup vs baseline: 1.7333x; 1.7333x over previous
//
#include <hip/hip_runtime.h>
#include <cstddef>

#define Bx 2
#define Tn 4096
#define Hh 8

typedef unsigned short u16;
typedef unsigned int u32;
typedef __attribute__((ext_vector_type(8))) short short8;
typedef __attribute__((ext_vector_type(4))) float f32x4;

__device__ __forceinline__ float bf2f(u16 u) {
  u32 x = ((u32)u) << 16;
  return __uint_as_float(x);
}
__device__ __forceinline__ u16 f2bf(float f) {
  u32 x = __float_as_uint(f);
  u32 lsb = (x >> 16) & 1;
  x += 0x7fffu + lsb;
  return (u16)(x >> 16);
}
__device__ __forceinline__ u32 pack2(float a, float b) {
  return (u32)f2bf(a) | ((u32)f2bf(b) << 16);
}
__device__ __forceinline__ short8 cvt8(float4 f0, float4 f1) {
  uint4 p;
  p.x = pack2(f0.x, f0.y);
  p.y = pack2(f0.z, f0.w);
  p.z = pack2(f1.x, f1.y);
  p.w = pack2(f1.z, f1.w);
  return *(short8*)&p;
}
__device__ __forceinline__ void async16(u16* lds, const u16* g) {
  __builtin_amdgcn_global_load_lds((const __attribute__((address_space(1))) void*)g,
                                   (__attribute__((address_space(3))) void*)lds, 16, 0, 0);
}

// ---------------------------------------------------------------------------
// f32 -> bf16 elementwise convert
// ---------------------------------------------------------------------------
__global__ __launch_bounds__(256) void conv_bf16(const float* __restrict__ X,
                                                 u16* __restrict__ Xb) {
  int i = (blockIdx.x * 256 + threadIdx.x) * 8;
  float4 v0 = *(const float4*)&X[i];
  float4 v1 = *(const float4*)&X[i + 4];
  uint4 pv;
  pv.x = pack2(v0.x, v0.y);
  pv.y = pack2(v0.z, v0.w);
  pv.z = pack2(v1.x, v1.y);
  pv.w = pack2(v1.z, v1.w);
  *(uint4*)&Xb[i] = pv;
}

// ---------------------------------------------------------------------------
// Transpose-convert: W[K][N] f32 -> WT[N][K] bf16. 64x64 tiles.
// ---------------------------------------------------------------------------
__global__ __launch_bounds__(256) void transpose_bf16(const float* __restrict__ W,
                                                      u16* __restrict__ WT,
                                                      int K, int N) {
  __shared__ float tile[64][68];
  int nb = blockIdx.x, kb = blockIdx.y;
  int tid = threadIdx.x;
  int r = tid >> 4, c4 = (tid & 15) * 4;
#pragma unroll
  for (int p = 0; p < 4; p++) {
    int k = kb * 64 + p * 16 + r;
    float4 v = *(const float4*)&W[(size_t)k * N + nb * 64 + c4];
    tile[p * 16 + r][c4] = v.x;
    tile[p * 16 + r][c4 + 1] = v.y;
    tile[p * 16 + r][c4 + 2] = v.z;
    tile[p * 16 + r][c4 + 3] = v.w;
  }
  __syncthreads();
  int rn = tid >> 2, ck = (tid & 3) * 16;
#pragma unroll
  for (int s = 0; s < 2; s++) {
    int k0 = ck + s * 8;
    uint4 pv;
    pv.x = pack2(tile[k0 + 0][rn], tile[k0 + 1][rn]);
    pv.y = pack2(tile[k0 + 2][rn], tile[k0 + 3][rn]);
    pv.z = pack2(tile[k0 + 4][rn], tile[k0 + 5][rn]);
    pv.w = pack2(tile[k0 + 6][rn], tile[k0 + 7][rn]);
    *(uint4*)&WT[(size_t)(nb * 64 + rn) * K + kb * 64 + k0] = pv;
  }
}

// ---------------------------------------------------------------------------
// bf16 MFMA GEMM (m97 pattern). EPI=1: qkvz split epi. EPI=0: f32 store.
// ---------------------------------------------------------------------------
template<int EPI>
__global__ __launch_bounds__(256) void gemm_mfma(const u16* __restrict__ A,
                                                 const u16* __restrict__ Bt,
                                                 u16* __restrict__ O1,
                                                 u16* __restrict__ O2,
                                                 float* __restrict__ O3,
                                                 int Nfull) {
  const int K = 1024;
  __shared__ u16 As[128 * 32];
  __shared__ u16 Bs[128 * 32];
  int bn = blockIdx.x, bm = blockIdx.y;
  int tid = threadIdx.x;
  int wave = tid >> 6, lane = tid & 63;
  int wr = wave >> 1, wc = wave & 1;

  f32x4 acc[4][4];
#pragma unroll
  for (int i = 0; i < 4; i++)
#pragma unroll
    for (int j = 0; j < 4; j++) acc[i][j] = (f32x4){0.f, 0.f, 0.f, 0.f};

  const u16* Ab = A + (size_t)(bm * 128 + wave * 32 + (lane >> 2)) * K + (lane & 3) * 8;
  const u16* Bb = Bt + (size_t)(bn * 128 + wave * 32 + (lane >> 2)) * K + (lane & 3) * 8;
  u16* AsW = &As[(wave * 32) * 32];
  u16* BsW = &Bs[(wave * 32) * 32];

  int m_lane = lane & 15, k_lane = (lane >> 4) * 8;
  const u16* arow0 = &As[(wr * 64 + m_lane) * 32 + k_lane];
  const u16* brow0 = &Bs[(wc * 64 + m_lane) * 32 + k_lane];

  for (int kk = 0; kk < K; kk += 32) {
    __syncthreads();
    async16(AsW, Ab + kk);
    async16(AsW + 16 * 32, Ab + 16 * K + kk);
    async16(BsW, Bb + kk);
    async16(BsW + 16 * 32, Bb + 16 * K + kk);
    __syncthreads();
    short8 a[4], b[4];
#pragma unroll
    for (int t = 0; t < 4; t++) a[t] = *(const short8*)(arow0 + t * 16 * 32);
#pragma unroll
    for (int t = 0; t < 4; t++) b[t] = *(const short8*)(brow0 + t * 16 * 32);
#pragma unroll
    for (int i = 0; i < 4; i++)
#pragma unroll
      for (int j = 0; j < 4; j++)
        acc[i][j] = __builtin_amdgcn_mfma_f32_16x16x32_bf16(a[i], b[j], acc[i][j], 0, 0, 0);
  }

  int n0 = bn * 128;
  int cbase = wc * 64 + (lane & 15);
  int rbase = bm * 128 + wr * 64 + ((lane >> 4) * 4);
  if (EPI == 1) {
    int h = n0 >> 9, sub = (n0 >> 7) & 3;
    u16* dst;
    size_t stride;
    if (sub < 3) { dst = O1 + (size_t)(sub * 1024 + h * 128); stride = 3072; }
    else         { dst = O2 + (size_t)(h * 128);              stride = 1024; }
#pragma unroll
    for (int i = 0; i < 4; i++)
#pragma unroll
      for (int j = 0; j < 4; j++)
#pragma unroll
        for (int r = 0; r < 4; r++)
          dst[(size_t)(rbase + i * 16 + r) * stride + cbase + j * 16] = f2bf(acc[i][j][r]);
  } else {
#pragma unroll
    for (int i = 0; i < 4; i++)
#pragma unroll
      for (int j = 0; j < 4; j++)
#pragma unroll
        for (int r = 0; r < 4; r++)
          O3[(size_t)(rbase + i * 16 + r) * Nfull + n0 + cbase + j * 16] = acc[i][j][r];
  }
}

// ---------------------------------------------------------------------------
// ba = x @ W_ba then beta = sigmoid(b), g = -exp(A)*softplus(a+dt)
// ---------------------------------------------------------------------------
__global__ __launch_bounds__(128) void ba_kernel(const float* __restrict__ x,
                                                 const float* __restrict__ Wba,
                                                 const float* __restrict__ dtb,
                                                 const float* __restrict__ Alog,
                                                 float* __restrict__ betab,
                                                 float* __restrict__ gb) {
  __shared__ float xs[1024];
  __shared__ float part[8][16];
  int row = blockIdx.x, tid = threadIdx.x;
#pragma unroll
  for (int r = 0; r < 2; r++) {
    int f4 = r * 128 + tid;
    *(float4*)&xs[f4 * 4] = *(const float4*)&x[(size_t)row * 1024 + f4 * 4];
  }
  __syncthreads();
  int col = tid & 15, seg = tid >> 4;
  float a = 0.f;
  for (int k = seg * 128; k < seg * 128 + 128; k++) a += xs[k] * Wba[k * 16 + col];
  part[seg][col] = a;
  __syncthreads();
  if (tid < 8) {
    float bval = 0.f, aval = 0.f;
#pragma unroll
    for (int q = 0; q < 8; q++) { bval += part[q][tid * 2]; aval += part[q][tid * 2 + 1]; }
    betab[(size_t)row * 8 + tid] = 1.f / (1.f + expf(-bval));
    float spin = aval + dtb[tid];
    float sp = (spin > 20.f) ? spin : log1pf(expf(spin));
    gb[(size_t)row * 8 + tid] = -expf(Alog[tid]) * sp;
  }
}

// ---------------------------------------------------------------------------
// Per-chunk prep. One block per (chunk, bh). 256 threads.
// ---------------------------------------------------------------------------
__global__ __launch_bounds__(256) void prep(const u16* __restrict__ mixed,
                                            const float* __restrict__ cw,
                                            const float* __restrict__ gbuf,
                                            const float* __restrict__ betabuf,
                                            u16* __restrict__ qg,
                                            u16* __restrict__ kdT,
                                            u16* __restrict__ vnT,
                                            u16* __restrict__ kcum,
                                            u16* __restrict__ attn,
                                            float* __restrict__ egl) {
  __shared__ float sK[64 * 132];
  __shared__ float sQ[32 * 132];  // reused as tri[64*66]
  __shared__ float gc_s[64], bet_s[64], inv_s[64], red_s[256];

  int n = blockIdx.x, bh = blockIdx.y;
  int b = bh >> 3, h = bh & 7;
  int t0 = n * 64;
  int tid = threadIdx.x;
  const int rowg0 = b * Tn + t0;
  const int rowh0 = bh * Tn + t0;
  const size_t tbase = (size_t)(bh * 64 + n) * 8192;

  if (tid < 64) {
    red_s[tid] = gbuf[(size_t)(rowg0 + tid) * 8 + h];
    bet_s[tid] = betabuf[(size_t)(rowg0 + tid) * 8 + h];
  }
  __syncthreads();
  if (tid == 0) {
    float s = 0.f;
    for (int i = 0; i < 64; i++) { s += red_s[i]; gc_s[i] = s; }
  }
  __syncthreads();
  float gl = gc_s[63];

  // conv k -> sK, silu
  for (int r = 0; r < 32; r++) {
    int idx = r * 256 + tid;
    int i = idx >> 7, d = idx & 127;
    int col = 1024 + h * 128 + d;
    float a = 0.f;
    int tg = t0 + i - 3;
#pragma unroll
    for (int tap = 0; tap < 4; tap++)
      if (tg + tap >= 0) a += bf2f(mixed[(size_t)(b * Tn + tg + tap) * 3072 + col]) * cw[col * 4 + tap];
    a = a / (1.f + expf(-a));
    sK[i * 132 + d] = a;
  }
  __syncthreads();
  {
    int i = tid >> 2, p = tid & 3;
    float ss = 0.f;
    for (int d = p * 32; d < p * 32 + 32; d++) { float v = sK[i * 132 + d]; ss += v * v; }
    red_s[tid] = ss;
  }
  __syncthreads();
  if (tid < 64)
    inv_s[tid] = rsqrtf(red_s[tid * 4] + red_s[tid * 4 + 1] + red_s[tid * 4 + 2] + red_s[tid * 4 + 3] + 1e-6f);
  __syncthreads();
  for (int r = 0; r < 32; r++) {
    int idx = r * 256 + tid;
    int i = idx >> 7, d = idx & 127;
    sK[i * 132 + d] *= inv_s[i];
  }
  __syncthreads();
  // kdT[dk][m] = kn * exp(gl - gc_i)
  for (int r = 0; r < 32; r++) {
    int idx = r * 256 + tid;
    int d = idx >> 6, i = idx & 63;
    kdT[tbase + d * 64 + i] = f2bf(sK[i * 132 + d] * expf(gl - gc_s[i]));
  }

  // q halves
  for (int half = 0; half < 2; half++) {
    int i0 = half * 32;
    __syncthreads();
    for (int r = 0; r < 16; r++) {
      int idx = r * 256 + tid;
      int li = idx >> 7, d = idx & 127;
      int i = i0 + li;
      int col = h * 128 + d;
      float a = 0.f;
      int tg = t0 + i - 3;
#pragma unroll
      for (int tap = 0; tap < 4; tap++)
        if (tg + tap >= 0) a += bf2f(mixed[(size_t)(b * Tn + tg + tap) * 3072 + col]) * cw[col * 4 + tap];
      a = a / (1.f + expf(-a));
      sQ[li * 132 + d] = a;
    }
    __syncthreads();
    if (tid < 128) {
      int li = tid >> 2, p = tid & 3;
      float ss = 0.f;
      for (int d = p * 32; d < p * 32 + 32; d++) { float v = sQ[li * 132 + d]; ss += v * v; }
      red_s[tid] = ss;
    }
    __syncthreads();
    if (tid < 32)
      inv_s[tid] = rsqrtf(red_s[tid * 4] + red_s[tid * 4 + 1] + red_s[tid * 4 + 2] + red_s[tid * 4 + 3] + 1e-6f) *
                   0.08838834764831845f;
    __syncthreads();
    for (int r = 0; r < 16; r++) {
      int idx = r * 256 + tid;
      int li = idx >> 7, d = idx & 127;
      sQ[li * 132 + d] *= inv_s[li];
    }
    __syncthreads();
    for (int r = 0; r < 16; r++) {
      int idx = r * 256 + tid;
      int li = idx >> 7, d = idx & 127;
      int i = i0 + li;
      qg[(size_t)(rowh0 + i) * 128 + d] = f2bf(sQ[li * 132 + d] * expf(gc_s[i]));
    }
    // attn rows
    {
      int rp = tid >> 4, cg = tid & 15;
      float a_acc[2][4] = {};
      for (int d4 = 0; d4 < 128; d4 += 4) {
        float4 q0 = *(float4*)&sQ[(rp * 2 + 0) * 132 + d4];
        float4 q1 = *(float4*)&sQ[(rp * 2 + 1) * 132 + d4];
#pragma unroll
        for (int jj = 0; jj < 4; jj++) {
          float4 kv = *(float4*)&sK[(cg * 4 + jj) * 132 + d4];
          a_acc[0][jj] += q0.x * kv.x + q0.y * kv.y + q0.z * kv.z + q0.w * kv.w;
          a_acc[1][jj] += q1.x * kv.x + q1.y * kv.y + q1.z * kv.z + q1.w * kv.w;
        }
      }
#pragma unroll
      for (int rr = 0; rr < 2; rr++) {
        int i = i0 + rp * 2 + rr;
        float o[4];
#pragma unroll
        for (int jj = 0; jj < 4; jj++) {
          int j = cg * 4 + jj;
          o[jj] = (j <= i) ? a_acc[rr][jj] * expf(gc_s[i] - gc_s[j]) : 0.f;
        }
        uint2 ov;
        ov.x = pack2(o[0], o[1]);
        ov.y = pack2(o[2], o[3]);
        *(uint2*)&attn[(size_t)(bh * 64 + n) * 4096 + i * 64 + cg * 4] = ov;
      }
    }
  }

  // tri into sQ region (stride 66)
  float* tri = sQ;
  {
    int rp = tid >> 4, cg = tid & 15;
    float t_acc[4][4] = {};
    for (int d4 = 0; d4 < 128; d4 += 4) {
      float4 ka[4];
#pragma unroll
      for (int rr = 0; rr < 4; rr++) ka[rr] = *(float4*)&sK[(rp * 4 + rr) * 132 + d4];
#pragma unroll
      for (int jj = 0; jj < 4; jj++) {
        float4 kb = *(float4*)&sK[(cg * 4 + jj) * 132 + d4];
#pragma unroll
        for (int rr = 0; rr < 4; rr++)
          t_acc[rr][jj] += ka[rr].x * kb.x + ka[rr].y * kb.y + ka[rr].z * kb.z + ka[rr].w * kb.w;
      }
    }
    __syncthreads();
#pragma unroll
    for (int rr = 0; rr < 4; rr++)
#pragma unroll
      for (int jj = 0; jj < 4; jj++) {
        int i = rp * 4 + rr, j = cg * 4 + jj;
        tri[i * 66 + j] = (j < i) ? bet_s[i] * expf(gc_s[i] - gc_s[j]) * t_acc[rr][jj] : 0.f;
      }
  }
  __syncthreads();

  // forward substitution, both RHS
  {
    int mat = tid >> 7, c = tid & 127;
    float x[64];
    if (mat == 0) {
#pragma unroll
      for (int i = 0; i < 64; i++) x[i] = sK[i * 132 + c] * bet_s[i] * expf(gc_s[i]);
    } else {
      int col = 2048 + h * 128 + c;
      for (int i = 0; i < 64; i++) {
        float a = 0.f;
        int tg = t0 + i - 3;
#pragma unroll
        for (int tap = 0; tap < 4; tap++)
          if (tg + tap >= 0) a += bf2f(mixed[(size_t)(b * Tn + tg + tap) * 3072 + col]) * cw[col * 4 + tap];
        a = a / (1.f + expf(-a));
        x[i] = a * bet_s[i];
      }
    }
#pragma unroll
    for (int i = 1; i < 64; i++) {
      float s = x[i];
#pragma unroll
      for (int l = 0; l < i; l++) s -= tri[i * 66 + l] * x[l];
      x[i] = s;
    }
    if (mat == 0) {
#pragma unroll
      for (int i = 0; i < 64; i++) kcum[(size_t)(rowh0 + i) * 128 + c] = f2bf(x[i]);
    } else {
#pragma unroll
      for (int i = 0; i < 64; i += 2)
        *(u32*)&vnT[tbase + c * 64 + i] = pack2(x[i], x[i + 1]);
    }
  }
  if (tid == 0) egl[bh * 64 + n] = expf(gl);
}

// ---------------------------------------------------------------------------
// MFMA inter-chunk scan, software-pipelined. Grid: 128 blocks x 64 threads.
// blk&15 = bh, blk>>4 = dv-tile  => the 8 tile-blocks of a bh share blk%8
// (same XCD) for L2 line sharing. One wave per block: no barriers; ~1 wave/CU
// so VGPR budget is huge — kcum/vnT prefetched one chunk ahead in registers,
// qg/attn/kdT issued at iteration top and consumed in the second half.
// ---------------------------------------------------------------------------
__global__ __launch_bounds__(64) void scan_mfma(const u16* __restrict__ qg,
                                                const u16* __restrict__ kdT,
                                                const u16* __restrict__ vnT,
                                                const u16* __restrict__ kcum,
                                                const u16* __restrict__ attn,
                                                const float* __restrict__ egl,
                                                float* __restrict__ core) {
  __shared__ float ST[16 * 132];  // S^T [dv16][dk128] fp32
  __shared__ float VN[16 * 68];   // vn^T [dv16][m64] fp32
  int blk = blockIdx.x;
  int bh = blk & 15, tile = blk >> 4;
  int dv0 = tile * 16;
  int b = bh >> 3, h = bh & 7;
  int lane = threadIdx.x;
  int q = lane >> 4, col = lane & 15;

  for (int r = lane; r < 16 * 132; r += 64) ST[r] = 0.f;

  // prefetch chunk 0: kcum fragments + vnT slice
  short8 kcf[16];
  uint2 vtf[4];
  {
    const u16* kc_b = kcum + (size_t)(bh * Tn) * 128;
    const u16* vt_b = vnT + (size_t)(bh * 64) * 8192 + (size_t)(dv0 + col) * 64;
#pragma unroll
    for (int mt = 0; mt < 4; mt++) {
#pragma unroll
      for (int kt = 0; kt < 4; kt++)
        kcf[mt * 4 + kt] = *(const short8*)(kc_b + (size_t)(mt * 16 + col) * 128 + kt * 32 + q * 8);
      vtf[mt] = *(const uint2*)(vt_b + mt * 16 + q * 4);
    }
  }

  for (int n = 0; n < 64; n++) {
    const u16* qg_b = qg + (size_t)(bh * Tn + n * 64) * 128;
    const u16* at_b = attn + (size_t)(bh * 64 + n) * 4096;
    const u16* kt_b = kdT + (size_t)(bh * 64 + n) * 8192;
    float eg = egl[bh * 64 + n];

    // current-chunk loads for the second half — issue NOW, consume later
    short8 qgf[16], atf[8], ktf[16];
#pragma unroll
    for (int mt = 0; mt < 4; mt++)
#pragma unroll
      for (int kt = 0; kt < 4; kt++)
        qgf[mt * 4 + kt] = *(const short8*)(qg_b + (size_t)(mt * 16 + col) * 128 + kt * 32 + q * 8);
#pragma unroll
    for (int mt = 0; mt < 4; mt++)
#pragma unroll
      for (int kt2 = 0; kt2 < 2; kt2++)
        atf[mt * 2 + kt2] = *(const short8*)(at_b + (mt * 16 + col) * 64 + kt2 * 32 + q * 8);
#pragma unroll
    for (int t = 0; t < 8; t++)
#pragma unroll
      for (int kt2 = 0; kt2 < 2; kt2++)
        ktf[t * 2 + kt2] = *(const short8*)(kt_b + (size_t)(t * 16 + col) * 64 + kt2 * 32 + q * 8);

    // prefetch NEXT chunk's kcum/vnT (index clamped at the tail; values unused)
    short8 kcn[16];
    uint2 vtn[4];
    {
      int np = (n < 63) ? n + 1 : n;
      const u16* kc_n = kcum + (size_t)(bh * Tn + np * 64) * 128;
      const u16* vt_n = vnT + (size_t)(bh * 64 + np) * 8192 + (size_t)(dv0 + col) * 64;
#pragma unroll
      for (int mt = 0; mt < 4; mt++) {
#pragma unroll
        for (int kt = 0; kt < 4; kt++)
          kcn[mt * 4 + kt] = *(const short8*)(kc_n + (size_t)(mt * 16 + col) * 128 + kt * 32 + q * 8);
        vtn[mt] = *(const uint2*)(vt_n + mt * 16 + q * 4);
      }
    }

    // S as B-fragments (bf16) + negated copy
    short8 sb[4], sbn[4];
#pragma unroll
    for (int kt = 0; kt < 4; kt++) {
      float4 f0 = *(float4*)&ST[col * 132 + kt * 32 + q * 8];
      float4 f1 = *(float4*)&ST[col * 132 + kt * 32 + q * 8 + 4];
      sb[kt] = cvt8(f0, f1);
      uint4 u = *(uint4*)&sb[kt];
      u.x ^= 0x80008000u; u.y ^= 0x80008000u; u.z ^= 0x80008000u; u.w ^= 0x80008000u;
      sbn[kt] = *(short8*)&u;
    }

    // vn = vnew - kcum @ S  (prefetched operands: starts immediately)
    f32x4 vn[4];
#pragma unroll
    for (int mt = 0; mt < 4; mt++) {
      f32x4 a0;
      a0[0] = bf2f(vtf[mt].x & 0xffff); a0[1] = bf2f(vtf[mt].x >> 16);
      a0[2] = bf2f(vtf[mt].y & 0xffff); a0[3] = bf2f(vtf[mt].y >> 16);
#pragma unroll
      for (int kt = 0; kt < 4; kt++)
        a0 = __builtin_amdgcn_mfma_f32_16x16x32_bf16(kcf[mt * 4 + kt], sbn[kt], a0, 0, 0, 0);
      vn[mt] = a0;
    }
#pragma unroll
    for (int mt = 0; mt < 4; mt++)
      *(f32x4*)&VN[col * 68 + mt * 16 + q * 4] = vn[mt];
    short8 vb[2];
#pragma unroll
    for (int kt2 = 0; kt2 < 2; kt2++) {
      float4 f0 = *(float4*)&VN[col * 68 + kt2 * 32 + q * 8];
      float4 f1 = *(float4*)&VN[col * 68 + kt2 * 32 + q * 8 + 4];
      vb[kt2] = cvt8(f0, f1);
    }

    // out = qg @ S + attn @ vn
#pragma unroll
    for (int mt = 0; mt < 4; mt++) {
      f32x4 o = (f32x4){0.f, 0.f, 0.f, 0.f};
#pragma unroll
      for (int kt = 0; kt < 4; kt++)
        o = __builtin_amdgcn_mfma_f32_16x16x32_bf16(qgf[mt * 4 + kt], sb[kt], o, 0, 0, 0);
#pragma unroll
      for (int kt2 = 0; kt2 < 2; kt2++)
        o = __builtin_amdgcn_mfma_f32_16x16x32_bf16(atf[mt * 2 + kt2], vb[kt2], o, 0, 0, 0);
      size_t rowb = (size_t)(b * Tn) + n * 64 + mt * 16 + q * 4;
#pragma unroll
      for (int r2 = 0; r2 < 4; r2++)
        core[(rowb + r2) * 1024 + h * 128 + dv0 + col] = o[r2];
    }

    // S = eg*S + kdT @ vn
#pragma unroll
    for (int t = 0; t < 8; t++) {
      f32x4 s0 = *(f32x4*)&ST[col * 132 + t * 16 + q * 4];
      s0[0] *= eg; s0[1] *= eg; s0[2] *= eg; s0[3] *= eg;
#pragma unroll
      for (int kt2 = 0; kt2 < 2; kt2++)
        s0 = __builtin_amdgcn_mfma_f32_16x16x32_bf16(ktf[t * 2 + kt2], vb[kt2], s0, 0, 0, 0);
      *(f32x4*)&ST[col * 132 + t * 16 + q * 4] = s0;
    }

    // rotate prefetch registers
#pragma unroll
    for (int i = 0; i < 16; i++) kcf[i] = kcn[i];
#pragma unroll
    for (int i = 0; i < 4; i++) vtf[i] = vtn[i];
  }
}

// ---------------------------------------------------------------------------
// Gated RMSNorm; writes bf16 coreb (A-operand of out GEMM).
// ---------------------------------------------------------------------------
__global__ __launch_bounds__(256) void gnorm(const float* __restrict__ core,
                                             const u16* __restrict__ z,
                                             const float* __restrict__ nw,
                                             u16* __restrict__ coreb) {
  __shared__ float red[256];
  __shared__ float rstd[8];
  int row = blockIdx.x, tid = threadIdx.x;
  float4 c4 = *(const float4*)&core[(size_t)row * 1024 + tid * 4];
  uint2 zl = *(const uint2*)&z[(size_t)row * 1024 + tid * 4];
  float4 z4;
  z4.x = bf2f(zl.x & 0xffff); z4.y = bf2f(zl.x >> 16);
  z4.z = bf2f(zl.y & 0xffff); z4.w = bf2f(zl.y >> 16);
  red[tid] = c4.x * c4.x + c4.y * c4.y + c4.z * c4.z + c4.w * c4.w;
  __syncthreads();
  if (tid < 8) {
    float s = 0.f;
    for (int t2 = tid * 32; t2 < tid * 32 + 32; t2++) s += red[t2];
    rstd[tid] = rsqrtf(s * (1.f / 128.f) + 1e-6f);
  }
  __syncthreads();
  float rs = rstd[tid >> 5];
  int d0 = (tid * 4) & 127;
  float4 w4 = *(const float4*)&nw[d0];
  float4 o;
  o.x = c4.x * rs * w4.x * (z4.x / (1.f + expf(-z4.x)));
  o.y = c4.y * rs * w4.y * (z4.y / (1.f + expf(-z4.y)));
  o.z = c4.z * rs * w4.z * (z4.z / (1.f + expf(-z4.z)));
  o.w = c4.w * rs * w4.w * (z4.w / (1.f + expf(-z4.w)));
  uint2 pv;
  pv.x = pack2(o.x, o.y);
  pv.y = pack2(o.z, o.w);
  *(uint2*)&coreb[(size_t)row * 1024 + tid * 4] = pv;
}

// ---------------------------------------------------------------------------
extern "C" void kernel_launch(void* const* d_in, const int* in_sizes, int n_in,
                              void* d_out, int out_size, void* d_ws, size_t ws_size,
                              hipStream_t stream) {
  const float* x     = (const float*)d_in[0];
  const float* Wqkvz = (const float*)d_in[1];
  const float* Wba   = (const float*)d_in[2];
  const float* convw = (const float*)d_in[3];
  const float* dtb   = (const float*)d_in[4];
  const float* Alog  = (const float*)d_in[5];
  const float* nw    = (const float*)d_in[6];
  const float* Wout  = (const float*)d_in[7];
  float* out = (float*)d_out;

  // Workspace layout, total 143,134,720 B. Aliases lifetime-disjoint.
  char* w = (char*)d_ws;
  u16*   mixed = (u16*)w;                      // 50,331,648 B
  float* core  = (float*)w;                    // 33,554,432 B (aliases mixed)
  u16*   coreb = (u16*)(w + 33554432);         // 16,777,216 B
  u16*   zb    = (u16*)(w + 50331648);         // 16,777,216 B
  float* betab = (float*)(w + 67108864);       //    262,144 B
  float* gb    = (float*)(w + 67371008);       //    262,144 B
  u16*   qgB   = (u16*)(w + 67633152);         // 16,777,216 B
  u16*   xb    = (u16*)(w + 67633152);         // (alias, dead before prep)
  u16*   kdTB  = (u16*)(w + 84410368);         // 16,777,216 B
  u16*   WqT   = (u16*)(w + 84410368);         // (alias, dead before prep)
  u16*   vnTB  = (u16*)(w + 101187584);        // 16,777,216 B
  u16*   kcB   = (u16*)(w + 117964800);        // 16,777,216 B
  u16*   WoT   = (u16*)(w + 117964800);        // (alias, written after scan)
  u16*   atB   = (u16*)(w + 134742016);        //  8,388,608 B
  float* eglB  = (float*)(w + 143130624);      //      4,096 B

  conv_bf16<<<dim3(4096), 256, 0, stream>>>(x, xb);
  transpose_bf16<<<dim3(64, 16), 256, 0, stream>>>(Wqkvz, WqT, 1024, 4096);
  gemm_mfma<1><<<dim3(32, 64), 256, 0, stream>>>(xb, WqT, mixed, zb, nullptr, 4096);
  ba_kernel<<<dim3(8192), 128, 0, stream>>>(x, Wba, dtb, Alog, betab, gb);
  prep<<<dim3(64, 16), 256, 0, stream>>>(mixed, convw, gb, betab, qgB, kdTB, vnTB, kcB, atB, eglB);
  scan_mfma<<<dim3(128), 64, 0, stream>>>(qgB, kdTB, vnTB, kcB, atB, eglB, core);
  transpose_bf16<<<dim3(16, 16), 256, 0, stream>>>(Wout, WoT, 1024, 1024);
  gnorm<<<dim3(8192), 256, 0, stream>>>(core, zb, nw, coreb);
  gemm_mfma<0><<<dim3(8, 64), 256, 0, stream>>>(coreb, WoT, nullptr, nullptr, out, 1024);
}

// Round 7
// 522.824 us; speedup vs baseline: 3.1528x; 1.8190x over previous
//
#include <hip/hip_runtime.h>
#include <cstddef>

#define Bx 2
#define Tn 4096
#define Hh 8

typedef unsigned short u16;
typedef unsigned int u32;
typedef __attribute__((ext_vector_type(8))) short short8;
typedef __attribute__((ext_vector_type(4))) float f32x4;

__device__ __forceinline__ float bf2f(u16 u) {
  u32 x = ((u32)u) << 16;
  return __uint_as_float(x);
}
__device__ __forceinline__ u16 f2bf(float f) {
  u32 x = __float_as_uint(f);
  u32 lsb = (x >> 16) & 1;
  x += 0x7fffu + lsb;
  return (u16)(x >> 16);
}
__device__ __forceinline__ u32 pack2(float a, float b) {
  return (u32)f2bf(a) | ((u32)f2bf(b) << 16);
}
__device__ __forceinline__ short8 cvt8(float4 f0, float4 f1) {
  uint4 p;
  p.x = pack2(f0.x, f0.y);
  p.y = pack2(f0.z, f0.w);
  p.z = pack2(f1.x, f1.y);
  p.w = pack2(f1.z, f1.w);
  return *(short8*)&p;
}
__device__ __forceinline__ void async16(u16* lds, const u16* g) {
  __builtin_amdgcn_global_load_lds((const __attribute__((address_space(1))) void*)g,
                                   (__attribute__((address_space(3))) void*)lds, 16, 0, 0);
}

// ---------------------------------------------------------------------------
// f32 -> bf16 elementwise convert
// ---------------------------------------------------------------------------
__global__ __launch_bounds__(256) void conv_bf16(const float* __restrict__ X,
                                                 u16* __restrict__ Xb) {
  int i = (blockIdx.x * 256 + threadIdx.x) * 8;
  float4 v0 = *(const float4*)&X[i];
  float4 v1 = *(const float4*)&X[i + 4];
  uint4 pv;
  pv.x = pack2(v0.x, v0.y);
  pv.y = pack2(v0.z, v0.w);
  pv.z = pack2(v1.x, v1.y);
  pv.w = pack2(v1.z, v1.w);
  *(uint4*)&Xb[i] = pv;
}

// ---------------------------------------------------------------------------
// Transpose-convert: W[K][N] f32 -> WT[N][K] bf16. 64x64 tiles.
// ---------------------------------------------------------------------------
__global__ __launch_bounds__(256) void transpose_bf16(const float* __restrict__ W,
                                                      u16* __restrict__ WT,
                                                      int K, int N) {
  __shared__ float tile[64][68];
  int nb = blockIdx.x, kb = blockIdx.y;
  int tid = threadIdx.x;
  int r = tid >> 4, c4 = (tid & 15) * 4;
#pragma unroll
  for (int p = 0; p < 4; p++) {
    int k = kb * 64 + p * 16 + r;
    float4 v = *(const float4*)&W[(size_t)k * N + nb * 64 + c4];
    tile[p * 16 + r][c4] = v.x;
    tile[p * 16 + r][c4 + 1] = v.y;
    tile[p * 16 + r][c4 + 2] = v.z;
    tile[p * 16 + r][c4 + 3] = v.w;
  }
  __syncthreads();
  int rn = tid >> 2, ck = (tid & 3) * 16;
#pragma unroll
  for (int s = 0; s < 2; s++) {
    int k0 = ck + s * 8;
    uint4 pv;
    pv.x = pack2(tile[k0 + 0][rn], tile[k0 + 1][rn]);
    pv.y = pack2(tile[k0 + 2][rn], tile[k0 + 3][rn]);
    pv.z = pack2(tile[k0 + 4][rn], tile[k0 + 5][rn]);
    pv.w = pack2(tile[k0 + 6][rn], tile[k0 + 7][rn]);
    *(uint4*)&WT[(size_t)(nb * 64 + rn) * K + kb * 64 + k0] = pv;
  }
}

// ---------------------------------------------------------------------------
// bf16 MFMA GEMM (m97 pattern). EPI=1: qkvz split epi. EPI=0: f32 store.
// ---------------------------------------------------------------------------
template<int EPI>
__global__ __launch_bounds__(256) void gemm_mfma(const u16* __restrict__ A,
                                                 const u16* __restrict__ Bt,
                                                 u16* __restrict__ O1,
                                                 u16* __restrict__ O2,
                                                 float* __restrict__ O3,
                                                 int Nfull) {
  const int K = 1024;
  __shared__ u16 As[128 * 32];
  __shared__ u16 Bs[128 * 32];
  int bn = blockIdx.x, bm = blockIdx.y;
  int tid = threadIdx.x;
  int wave = tid >> 6, lane = tid & 63;
  int wr = wave >> 1, wc = wave & 1;

  f32x4 acc[4][4];
#pragma unroll
  for (int i = 0; i < 4; i++)
#pragma unroll
    for (int j = 0; j < 4; j++) acc[i][j] = (f32x4){0.f, 0.f, 0.f, 0.f};

  const u16* Ab = A + (size_t)(bm * 128 + wave * 32 + (lane >> 2)) * K + (lane & 3) * 8;
  const u16* Bb = Bt + (size_t)(bn * 128 + wave * 32 + (lane >> 2)) * K + (lane & 3) * 8;
  u16* AsW = &As[(wave * 32) * 32];
  u16* BsW = &Bs[(wave * 32) * 32];

  int m_lane = lane & 15, k_lane = (lane >> 4) * 8;
  const u16* arow0 = &As[(wr * 64 + m_lane) * 32 + k_lane];
  const u16* brow0 = &Bs[(wc * 64 + m_lane) * 32 + k_lane];

  for (int kk = 0; kk < K; kk += 32) {
    __syncthreads();
    async16(AsW, Ab + kk);
    async16(AsW + 16 * 32, Ab + 16 * K + kk);
    async16(BsW, Bb + kk);
    async16(BsW + 16 * 32, Bb + 16 * K + kk);
    __syncthreads();
    short8 a[4], b[4];
#pragma unroll
    for (int t = 0; t < 4; t++) a[t] = *(const short8*)(arow0 + t * 16 * 32);
#pragma unroll
    for (int t = 0; t < 4; t++) b[t] = *(const short8*)(brow0 + t * 16 * 32);
#pragma unroll
    for (int i = 0; i < 4; i++)
#pragma unroll
      for (int j = 0; j < 4; j++)
        acc[i][j] = __builtin_amdgcn_mfma_f32_16x16x32_bf16(a[i], b[j], acc[i][j], 0, 0, 0);
  }

  int n0 = bn * 128;
  int cbase = wc * 64 + (lane & 15);
  int rbase = bm * 128 + wr * 64 + ((lane >> 4) * 4);
  if (EPI == 1) {
    int h = n0 >> 9, sub = (n0 >> 7) & 3;
    u16* dst;
    size_t stride;
    if (sub < 3) { dst = O1 + (size_t)(sub * 1024 + h * 128); stride = 3072; }
    else         { dst = O2 + (size_t)(h * 128);              stride = 1024; }
#pragma unroll
    for (int i = 0; i < 4; i++)
#pragma unroll
      for (int j = 0; j < 4; j++)
#pragma unroll
        for (int r = 0; r < 4; r++)
          dst[(size_t)(rbase + i * 16 + r) * stride + cbase + j * 16] = f2bf(acc[i][j][r]);
  } else {
#pragma unroll
    for (int i = 0; i < 4; i++)
#pragma unroll
      for (int j = 0; j < 4; j++)
#pragma unroll
        for (int r = 0; r < 4; r++)
          O3[(size_t)(rbase + i * 16 + r) * Nfull + n0 + cbase + j * 16] = acc[i][j][r];
  }
}

// ---------------------------------------------------------------------------
// ba = x @ W_ba then beta = sigmoid(b), g = -exp(A)*softplus(a+dt)
// ---------------------------------------------------------------------------
__global__ __launch_bounds__(128) void ba_kernel(const float* __restrict__ x,
                                                 const float* __restrict__ Wba,
                                                 const float* __restrict__ dtb,
                                                 const float* __restrict__ Alog,
                                                 float* __restrict__ betab,
                                                 float* __restrict__ gb) {
  __shared__ float xs[1024];
  __shared__ float part[8][16];
  int row = blockIdx.x, tid = threadIdx.x;
#pragma unroll
  for (int r = 0; r < 2; r++) {
    int f4 = r * 128 + tid;
    *(float4*)&xs[f4 * 4] = *(const float4*)&x[(size_t)row * 1024 + f4 * 4];
  }
  __syncthreads();
  int col = tid & 15, seg = tid >> 4;
  float a = 0.f;
  for (int k = seg * 128; k < seg * 128 + 128; k++) a += xs[k] * Wba[k * 16 + col];
  part[seg][col] = a;
  __syncthreads();
  if (tid < 8) {
    float bval = 0.f, aval = 0.f;
#pragma unroll
    for (int q = 0; q < 8; q++) { bval += part[q][tid * 2]; aval += part[q][tid * 2 + 1]; }
    betab[(size_t)row * 8 + tid] = 1.f / (1.f + expf(-bval));
    float spin = aval + dtb[tid];
    float sp = (spin > 20.f) ? spin : log1pf(expf(spin));
    gb[(size_t)row * 8 + tid] = -expf(Alog[tid]) * sp;
  }
}

// ---------------------------------------------------------------------------
// Per-chunk prep, v2: LDS-staged loads, MFMA attn/tri, float4-vectorized
// forward substitution, shuffle cumsum. One block per (chunk, bh), 256 thr.
// LDS ~53 KB -> 3 blocks/CU.
// ---------------------------------------------------------------------------
__global__ __launch_bounds__(256) void prep(const u16* __restrict__ mixed,
                                            const float* __restrict__ cw,
                                            const float* __restrict__ gbuf,
                                            const float* __restrict__ betabuf,
                                            u16* __restrict__ qg,
                                            u16* __restrict__ kdT,
                                            u16* __restrict__ vnT,
                                            u16* __restrict__ kcum,
                                            u16* __restrict__ attn,
                                            float* __restrict__ egl) {
  __shared__ __align__(16) u16 sRaw[67 * 128];   // 17152 B staging (k, q, v in turn)
  __shared__ __align__(16) u16 sKs[64 * 136];    // 17408 B k normed bf16
  __shared__ __align__(16) u16 sQs[64 * 136];    // 17408 B q normed bf16; aliased as tri f32[64*64]
  __shared__ float gc_s[64], egc_s[64], eglc_s[64], bet_s[64];
  float* red_s = (float*)sRaw;        // alias: only used when sRaw contents dead
  float* inv_s = (float*)sRaw + 256;  // alias (next 256 B)
  float* triL  = (float*)sQs;         // alias: tri written after attn consumed sQs

  int n = blockIdx.x, bh = blockIdx.y;
  int b = bh >> 3, h = bh & 7;
  int t0 = n * 64;
  int tid = threadIdx.x;
  const int rowg0 = b * Tn + t0;
  const int rowh0 = bh * Tn + t0;
  const size_t tbase = (size_t)(bh * 64 + n) * 8192;

  int wv = tid >> 6, lane = tid & 63;
  int m16 = lane & 15, q8 = (lane >> 4) * 8, qr = (lane >> 4) * 4;
  int srow = tid >> 4, scol8 = (tid & 15) * 8;

  // ---- stage k slice (rows t0-3..t0+63) ----
#pragma unroll
  for (int pass = 0; pass < 5; pass++) {
    int r = pass * 16 + srow;
    if (r < 67) {
      int t = t0 - 3 + r;
      uint4 v = make_uint4(0u, 0u, 0u, 0u);
      if (t >= 0) v = *(const uint4*)&mixed[(size_t)(b * Tn + t) * 3072 + 1024 + h * 128 + scol8];
      *(uint4*)&sRaw[r * 128 + scol8] = v;
    }
  }
  // ---- g/beta + shuffle cumsum + exp tables (wave 0) ----
  if (tid < 64) {
    float gv = gbuf[(size_t)(rowg0 + tid) * 8 + h];
    float bv = betabuf[(size_t)(rowg0 + tid) * 8 + h];
#pragma unroll
    for (int off = 1; off < 64; off <<= 1) {
      float o = __shfl_up(gv, off, 64);
      if (tid >= off) gv += o;
    }
    float gl = __shfl(gv, 63, 64);
    gc_s[tid] = gv;
    egc_s[tid] = expf(gv);
    eglc_s[tid] = expf(gl - gv);
    bet_s[tid] = bv;
    if (tid == 63) egl[bh * 64 + n] = expf(gl);
  }
  __syncthreads();

  // ---- conv k + silu -> sKs (bf16) ----
#pragma unroll
  for (int it = 0; it < 32; it++) {
    int idx = it * 256 + tid;
    int i = idx >> 7, d = idx & 127;
    int colw = (1024 + h * 128 + d) * 4;
    float a = 0.f;
#pragma unroll
    for (int tap = 0; tap < 4; tap++)
      a += bf2f(sRaw[(i + tap) * 128 + d]) * cw[colw + tap];
    a = a / (1.f + expf(-a));
    sKs[i * 136 + d] = f2bf(a);
  }
  __syncthreads();
  // ---- k row sumsq (red aliases sRaw: k-raw dead) ----
  {
    int i = tid >> 2, p = tid & 3;
    float ss = 0.f;
#pragma unroll
    for (int d = p * 32; d < p * 32 + 32; d += 2) {
      u32 w2 = *(const u32*)&sKs[i * 136 + d];
      float a = bf2f(w2 & 0xffff), b2 = bf2f(w2 >> 16);
      ss += a * a + b2 * b2;
    }
    red_s[tid] = ss;
  }
  __syncthreads();
  if (tid < 64)
    inv_s[tid] = rsqrtf(red_s[tid * 4] + red_s[tid * 4 + 1] + red_s[tid * 4 + 2] + red_s[tid * 4 + 3] + 1e-6f);
  __syncthreads();
  // ---- normalize k in place ----
#pragma unroll
  for (int it = 0; it < 16; it++) {
    int idx = it * 256 + tid;
    int i = idx >> 6, d2 = (idx & 63) * 2;
    u32 w2 = *(const u32*)&sKs[i * 136 + d2];
    float inv = inv_s[i];
    *(u32*)&sKs[i * 136 + d2] = pack2(bf2f(w2 & 0xffff) * inv, bf2f(w2 >> 16) * inv);
  }
  __syncthreads();
  // ---- kdT[d][i] = k_n * exp(gl-gc_i)  +  stage q slice ----
#pragma unroll
  for (int it = 0; it < 32; it++) {
    int idx = it * 256 + tid;
    int d = idx >> 6, i = idx & 63;
    kdT[tbase + d * 64 + i] = f2bf(bf2f(sKs[i * 136 + d]) * eglc_s[i]);
  }
#pragma unroll
  for (int pass = 0; pass < 5; pass++) {
    int r = pass * 16 + srow;
    if (r < 67) {
      int t = t0 - 3 + r;
      uint4 v = make_uint4(0u, 0u, 0u, 0u);
      if (t >= 0) v = *(const uint4*)&mixed[(size_t)(b * Tn + t) * 3072 + h * 128 + scol8];
      *(uint4*)&sRaw[r * 128 + scol8] = v;
    }
  }
  __syncthreads();
  // ---- conv q + silu -> sQs ----
#pragma unroll
  for (int it = 0; it < 32; it++) {
    int idx = it * 256 + tid;
    int i = idx >> 7, d = idx & 127;
    int colw = (h * 128 + d) * 4;
    float a = 0.f;
#pragma unroll
    for (int tap = 0; tap < 4; tap++)
      a += bf2f(sRaw[(i + tap) * 128 + d]) * cw[colw + tap];
    a = a / (1.f + expf(-a));
    sQs[i * 136 + d] = f2bf(a);
  }
  __syncthreads();
  // ---- q row sumsq ----
  {
    int i = tid >> 2, p = tid & 3;
    float ss = 0.f;
#pragma unroll
    for (int d = p * 32; d < p * 32 + 32; d += 2) {
      u32 w2 = *(const u32*)&sQs[i * 136 + d];
      float a = bf2f(w2 & 0xffff), b2 = bf2f(w2 >> 16);
      ss += a * a + b2 * b2;
    }
    red_s[tid] = ss;
  }
  __syncthreads();
  if (tid < 64)
    inv_s[tid] = rsqrtf(red_s[tid * 4] + red_s[tid * 4 + 1] + red_s[tid * 4 + 2] + red_s[tid * 4 + 3] + 1e-6f) *
                 0.08838834764831845f;  // dk^-0.5
  __syncthreads();
  // ---- normalize q in place + emit qg = q_n * exp(gc_i) ----
#pragma unroll
  for (int it = 0; it < 16; it++) {
    int idx = it * 256 + tid;
    int i = idx >> 6, d2 = (idx & 63) * 2;
    u32 w2 = *(const u32*)&sQs[i * 136 + d2];
    float inv = inv_s[i];
    float q0 = bf2f(w2 & 0xffff) * inv, q1 = bf2f(w2 >> 16) * inv;
    *(u32*)&sQs[i * 136 + d2] = pack2(q0, q1);
    float e = egc_s[i];
    *(u32*)&qg[(size_t)(rowh0 + i) * 128 + d2] = pack2(q0 * e, q1 * e);
  }
  __syncthreads();
  // ---- attn = tril(QK^T * decay) via MFMA; wave w does row band w*16.. ----
  {
    short8 qa[4];
#pragma unroll
    for (int kt = 0; kt < 4; kt++)
      qa[kt] = *(const short8*)&sQs[(wv * 16 + m16) * 136 + kt * 32 + q8];
    u16* atp = attn + (size_t)(bh * 64 + n) * 4096;
#pragma unroll
    for (int jt = 0; jt < 4; jt++) {
      int j = jt * 16 + m16;
      if (jt <= wv) {
        f32x4 o = (f32x4){0.f, 0.f, 0.f, 0.f};
#pragma unroll
        for (int kt = 0; kt < 4; kt++) {
          short8 kb = *(const short8*)&sKs[(jt * 16 + m16) * 136 + kt * 32 + q8];
          o = __builtin_amdgcn_mfma_f32_16x16x32_bf16(qa[kt], kb, o, 0, 0, 0);
        }
#pragma unroll
        for (int r = 0; r < 4; r++) {
          int i = wv * 16 + qr + r;
          float val = (j <= i) ? o[r] * expf(gc_s[i] - gc_s[j]) : 0.f;
          atp[i * 64 + j] = f2bf(val);
        }
      } else {
#pragma unroll
        for (int r = 0; r < 4; r++) atp[(wv * 16 + qr + r) * 64 + j] = 0;
      }
    }
  }
  __syncthreads();
  // ---- tri = tril(Kb K^T * decay, -1) via MFMA into triL (over sQs) ----
  {
    short8 ka[4];
#pragma unroll
    for (int kt = 0; kt < 4; kt++)
      ka[kt] = *(const short8*)&sKs[(wv * 16 + m16) * 136 + kt * 32 + q8];
#pragma unroll
    for (int jt = 0; jt < 4; jt++) {
      int j = jt * 16 + m16;
      if (jt <= wv) {
        f32x4 o = (f32x4){0.f, 0.f, 0.f, 0.f};
#pragma unroll
        for (int kt = 0; kt < 4; kt++) {
          short8 kb = *(const short8*)&sKs[(jt * 16 + m16) * 136 + kt * 32 + q8];
          o = __builtin_amdgcn_mfma_f32_16x16x32_bf16(ka[kt], kb, o, 0, 0, 0);
        }
#pragma unroll
        for (int r = 0; r < 4; r++) {
          int i = wv * 16 + qr + r;
          triL[i * 64 + j] = (j < i) ? bet_s[i] * expf(gc_s[i] - gc_s[j]) * o[r] : 0.f;
        }
      } else if (jt == wv + 1) {
#pragma unroll
        for (int r = 0; r < 4; r++) triL[(wv * 16 + qr + r) * 64 + j] = 0.f;  // solve over-read pad
      }
    }
  }
  // ---- stage v slice (sRaw free again) ----
  __syncthreads();
#pragma unroll
  for (int pass = 0; pass < 5; pass++) {
    int r = pass * 16 + srow;
    if (r < 67) {
      int t = t0 - 3 + r;
      uint4 v = make_uint4(0u, 0u, 0u, 0u);
      if (t >= 0) v = *(const uint4*)&mixed[(size_t)(b * Tn + t) * 3072 + 2048 + h * 128 + scol8];
      *(uint4*)&sRaw[r * 128 + scol8] = v;
    }
  }
  __syncthreads();

  // ---- forward substitution: (I+tri) X = RHS, two RHS across the block ----
  {
    int mat = tid >> 7, c = tid & 127;
    float x[64];
    if (mat == 0) {
#pragma unroll
      for (int i = 0; i < 64; i++)
        x[i] = bf2f(sKs[i * 136 + c]) * bet_s[i] * egc_s[i];
    } else {
      float cwv[4];
      int colw = (2048 + h * 128 + c) * 4;
#pragma unroll
      for (int tap = 0; tap < 4; tap++) cwv[tap] = cw[colw + tap];
#pragma unroll
      for (int i = 0; i < 64; i++) {
        float a = 0.f;
#pragma unroll
        for (int tap = 0; tap < 4; tap++)
          a += bf2f(sRaw[(i + tap) * 128 + c]) * cwv[tap];
        a = a / (1.f + expf(-a));
        x[i] = a * bet_s[i];
      }
    }
    // vectorized broadcast reads; 4 independent partial sums shorten the chain
#pragma unroll
    for (int i = 1; i < 64; i++) {
      float s0 = 0.f, s1 = 0.f, s2 = 0.f, s3 = 0.f;
#pragma unroll
      for (int l4 = 0; l4 < (i + 3) / 4; l4++) {
        float4 t4 = *(float4*)&triL[i * 64 + l4 * 4];
        s0 += t4.x * x[l4 * 4 + 0];
        s1 += t4.y * x[l4 * 4 + 1];
        s2 += t4.z * x[l4 * 4 + 2];
        s3 += t4.w * x[l4 * 4 + 3];
      }
      x[i] = x[i] - ((s0 + s1) + (s2 + s3));
    }
    if (mat == 0) {
#pragma unroll
      for (int i = 0; i < 64; i++) kcum[(size_t)(rowh0 + i) * 128 + c] = f2bf(x[i]);
    } else {
#pragma unroll
      for (int i = 0; i < 64; i += 2)
        *(u32*)&vnT[tbase + c * 64 + i] = pack2(x[i], x[i + 1]);
    }
  }
}

// ---------------------------------------------------------------------------
// MFMA inter-chunk scan, software-pipelined. Grid: 128 blocks x 64 threads.
// (unchanged from R6 — verified fast)
// ---------------------------------------------------------------------------
__global__ __launch_bounds__(64) void scan_mfma(const u16* __restrict__ qg,
                                                const u16* __restrict__ kdT,
                                                const u16* __restrict__ vnT,
                                                const u16* __restrict__ kcum,
                                                const u16* __restrict__ attn,
                                                const float* __restrict__ egl,
                                                float* __restrict__ core) {
  __shared__ float ST[16 * 132];
  __shared__ float VN[16 * 68];
  int blk = blockIdx.x;
  int bh = blk & 15, tile = blk >> 4;
  int dv0 = tile * 16;
  int b = bh >> 3, h = bh & 7;
  int lane = threadIdx.x;
  int q = lane >> 4, col = lane & 15;

  for (int r = lane; r < 16 * 132; r += 64) ST[r] = 0.f;

  short8 kcf[16];
  uint2 vtf[4];
  {
    const u16* kc_b = kcum + (size_t)(bh * Tn) * 128;
    const u16* vt_b = vnT + (size_t)(bh * 64) * 8192 + (size_t)(dv0 + col) * 64;
#pragma unroll
    for (int mt = 0; mt < 4; mt++) {
#pragma unroll
      for (int kt = 0; kt < 4; kt++)
        kcf[mt * 4 + kt] = *(const short8*)(kc_b + (size_t)(mt * 16 + col) * 128 + kt * 32 + q * 8);
      vtf[mt] = *(const uint2*)(vt_b + mt * 16 + q * 4);
    }
  }

  for (int n = 0; n < 64; n++) {
    const u16* qg_b = qg + (size_t)(bh * Tn + n * 64) * 128;
    const u16* at_b = attn + (size_t)(bh * 64 + n) * 4096;
    const u16* kt_b = kdT + (size_t)(bh * 64 + n) * 8192;
    float eg = egl[bh * 64 + n];

    short8 qgf[16], atf[8], ktf[16];
#pragma unroll
    for (int mt = 0; mt < 4; mt++)
#pragma unroll
      for (int kt = 0; kt < 4; kt++)
        qgf[mt * 4 + kt] = *(const short8*)(qg_b + (size_t)(mt * 16 + col) * 128 + kt * 32 + q * 8);
#pragma unroll
    for (int mt = 0; mt < 4; mt++)
#pragma unroll
      for (int kt2 = 0; kt2 < 2; kt2++)
        atf[mt * 2 + kt2] = *(const short8*)(at_b + (mt * 16 + col) * 64 + kt2 * 32 + q * 8);
#pragma unroll
    for (int t = 0; t < 8; t++)
#pragma unroll
      for (int kt2 = 0; kt2 < 2; kt2++)
        ktf[t * 2 + kt2] = *(const short8*)(kt_b + (size_t)(t * 16 + col) * 64 + kt2 * 32 + q * 8);

    short8 kcn[16];
    uint2 vtn[4];
    {
      int np = (n < 63) ? n + 1 : n;
      const u16* kc_n = kcum + (size_t)(bh * Tn + np * 64) * 128;
      const u16* vt_n = vnT + (size_t)(bh * 64 + np) * 8192 + (size_t)(dv0 + col) * 64;
#pragma unroll
      for (int mt = 0; mt < 4; mt++) {
#pragma unroll
        for (int kt = 0; kt < 4; kt++)
          kcn[mt * 4 + kt] = *(const short8*)(kc_n + (size_t)(mt * 16 + col) * 128 + kt * 32 + q * 8);
        vtn[mt] = *(const uint2*)(vt_n + mt * 16 + q * 4);
      }
    }

    short8 sb[4], sbn[4];
#pragma unroll
    for (int kt = 0; kt < 4; kt++) {
      float4 f0 = *(float4*)&ST[col * 132 + kt * 32 + q * 8];
      float4 f1 = *(float4*)&ST[col * 132 + kt * 32 + q * 8 + 4];
      sb[kt] = cvt8(f0, f1);
      uint4 u = *(uint4*)&sb[kt];
      u.x ^= 0x80008000u; u.y ^= 0x80008000u; u.z ^= 0x80008000u; u.w ^= 0x80008000u;
      sbn[kt] = *(short8*)&u;
    }

    f32x4 vn[4];
#pragma unroll
    for (int mt = 0; mt < 4; mt++) {
      f32x4 a0;
      a0[0] = bf2f(vtf[mt].x & 0xffff); a0[1] = bf2f(vtf[mt].x >> 16);
      a0[2] = bf2f(vtf[mt].y & 0xffff); a0[3] = bf2f(vtf[mt].y >> 16);
#pragma unroll
      for (int kt = 0; kt < 4; kt++)
        a0 = __builtin_amdgcn_mfma_f32_16x16x32_bf16(kcf[mt * 4 + kt], sbn[kt], a0, 0, 0, 0);
      vn[mt] = a0;
    }
#pragma unroll
    for (int mt = 0; mt < 4; mt++)
      *(f32x4*)&VN[col * 68 + mt * 16 + q * 4] = vn[mt];
    short8 vb[2];
#pragma unroll
    for (int kt2 = 0; kt2 < 2; kt2++) {
      float4 f0 = *(float4*)&VN[col * 68 + kt2 * 32 + q * 8];
      float4 f1 = *(float4*)&VN[col * 68 + kt2 * 32 + q * 8 + 4];
      vb[kt2] = cvt8(f0, f1);
    }

#pragma unroll
    for (int mt = 0; mt < 4; mt++) {
      f32x4 o = (f32x4){0.f, 0.f, 0.f, 0.f};
#pragma unroll
      for (int kt = 0; kt < 4; kt++)
        o = __builtin_amdgcn_mfma_f32_16x16x32_bf16(qgf[mt * 4 + kt], sb[kt], o, 0, 0, 0);
#pragma unroll
      for (int kt2 = 0; kt2 < 2; kt2++)
        o = __builtin_amdgcn_mfma_f32_16x16x32_bf16(atf[mt * 2 + kt2], vb[kt2], o, 0, 0, 0);
      size_t rowb = (size_t)(b * Tn) + n * 64 + mt * 16 + q * 4;
#pragma unroll
      for (int r2 = 0; r2 < 4; r2++)
        core[(rowb + r2) * 1024 + h * 128 + dv0 + col] = o[r2];
    }

#pragma unroll
    for (int t = 0; t < 8; t++) {
      f32x4 s0 = *(f32x4*)&ST[col * 132 + t * 16 + q * 4];
      s0[0] *= eg; s0[1] *= eg; s0[2] *= eg; s0[3] *= eg;
#pragma unroll
      for (int kt2 = 0; kt2 < 2; kt2++)
        s0 = __builtin_amdgcn_mfma_f32_16x16x32_bf16(ktf[t * 2 + kt2], vb[kt2], s0, 0, 0, 0);
      *(f32x4*)&ST[col * 132 + t * 16 + q * 4] = s0;
    }

#pragma unroll
    for (int i = 0; i < 16; i++) kcf[i] = kcn[i];
#pragma unroll
    for (int i = 0; i < 4; i++) vtf[i] = vtn[i];
  }
}

// ---------------------------------------------------------------------------
// Gated RMSNorm; writes bf16 coreb (A-operand of out GEMM).
// ---------------------------------------------------------------------------
__global__ __launch_bounds__(256) void gnorm(const float* __restrict__ core,
                                             const u16* __restrict__ z,
                                             const float* __restrict__ nw,
                                             u16* __restrict__ coreb) {
  __shared__ float red[256];
  __shared__ float rstd[8];
  int row = blockIdx.x, tid = threadIdx.x;
  float4 c4 = *(const float4*)&core[(size_t)row * 1024 + tid * 4];
  uint2 zl = *(const uint2*)&z[(size_t)row * 1024 + tid * 4];
  float4 z4;
  z4.x = bf2f(zl.x & 0xffff); z4.y = bf2f(zl.x >> 16);
  z4.z = bf2f(zl.y & 0xffff); z4.w = bf2f(zl.y >> 16);
  red[tid] = c4.x * c4.x + c4.y * c4.y + c4.z * c4.z + c4.w * c4.w;
  __syncthreads();
  if (tid < 8) {
    float s = 0.f;
    for (int t2 = tid * 32; t2 < tid * 32 + 32; t2++) s += red[t2];
    rstd[tid] = rsqrtf(s * (1.f / 128.f) + 1e-6f);
  }
  __syncthreads();
  float rs = rstd[tid >> 5];
  int d0 = (tid * 4) & 127;
  float4 w4 = *(const float4*)&nw[d0];
  float4 o;
  o.x = c4.x * rs * w4.x * (z4.x / (1.f + expf(-z4.x)));
  o.y = c4.y * rs * w4.y * (z4.y / (1.f + expf(-z4.y)));
  o.z = c4.z * rs * w4.z * (z4.z / (1.f + expf(-z4.z)));
  o.w = c4.w * rs * w4.w * (z4.w / (1.f + expf(-z4.w)));
  uint2 pv;
  pv.x = pack2(o.x, o.y);
  pv.y = pack2(o.z, o.w);
  *(uint2*)&coreb[(size_t)row * 1024 + tid * 4] = pv;
}

// ---------------------------------------------------------------------------
extern "C" void kernel_launch(void* const* d_in, const int* in_sizes, int n_in,
                              void* d_out, int out_size, void* d_ws, size_t ws_size,
                              hipStream_t stream) {
  const float* x     = (const float*)d_in[0];
  const float* Wqkvz = (const float*)d_in[1];
  const float* Wba   = (const float*)d_in[2];
  const float* convw = (const float*)d_in[3];
  const float* dtb   = (const float*)d_in[4];
  const float* Alog  = (const float*)d_in[5];
  const float* nw    = (const float*)d_in[6];
  const float* Wout  = (const float*)d_in[7];
  float* out = (float*)d_out;

  // Workspace layout, total 143,134,720 B. Aliases lifetime-disjoint.
  char* w = (char*)d_ws;
  u16*   mixed = (u16*)w;                      // 50,331,648 B
  float* core  = (float*)w;                    // 33,554,432 B (aliases mixed)
  u16*   coreb = (u16*)(w + 33554432);         // 16,777,216 B
  u16*   zb    = (u16*)(w + 50331648);         // 16,777,216 B
  float* betab = (float*)(w + 67108864);       //    262,144 B
  float* gb    = (float*)(w + 67371008);       //    262,144 B
  u16*   qgB   = (u16*)(w + 67633152);         // 16,777,216 B
  u16*   xb    = (u16*)(w + 67633152);         // (alias, dead before prep)
  u16*   kdTB  = (u16*)(w + 84410368);         // 16,777,216 B
  u16*   WqT   = (u16*)(w + 84410368);         // (alias, dead before prep)
  u16*   vnTB  = (u16*)(w + 101187584);        // 16,777,216 B
  u16*   kcB   = (u16*)(w + 117964800);        // 16,777,216 B
  u16*   WoT   = (u16*)(w + 117964800);        // (alias, written after scan)
  u16*   atB   = (u16*)(w + 134742016);        //  8,388,608 B
  float* eglB  = (float*)(w + 143130624);      //      4,096 B

  conv_bf16<<<dim3(4096), 256, 0, stream>>>(x, xb);
  transpose_bf16<<<dim3(64, 16), 256, 0, stream>>>(Wqkvz, WqT, 1024, 4096);
  gemm_mfma<1><<<dim3(32, 64), 256, 0, stream>>>(xb, WqT, mixed, zb, nullptr, 4096);
  ba_kernel<<<dim3(8192), 128, 0, stream>>>(x, Wba, dtb, Alog, betab, gb);
  prep<<<dim3(64, 16), 256, 0, stream>>>(mixed, convw, gb, betab, qgB, kdTB, vnTB, kcB, atB, eglB);
  scan_mfma<<<dim3(128), 64, 0, stream>>>(qgB, kdTB, vnTB, kcB, atB, eglB, core);
  transpose_bf16<<<dim3(16, 16), 256, 0, stream>>>(Wout, WoT, 1024, 1024);
  gnorm<<<dim3(8192), 256, 0, stream>>>(core, zb, nw, coreb);
  gemm_mfma<0><<<dim3(8, 64), 256, 0, stream>>>(coreb, WoT, nullptr, nullptr, out, 1024);
}